// Round 14
// baseline (720.328 us; speedup 1.0000x reference)
//
#include <hip/hip_runtime.h>
#include <hip/hip_bf16.h>
#include <hip/hip_cooperative_groups.h>

namespace cg = cooperative_groups;

// ---------------------------------------------------------------------------
// BlockedMLP: out = (relu(bsr(relu(x@W1^T+b1))+b2)) @ W3^T + b3
// Round 14: cooperative mega-kernel WITH CHECKED FALLBACK to the R12 path.
// R13's all-zero + fast-finish = launch rejected (not hang, not miscompute);
// this round checks the error and falls back. Fallback also banks a small
// win: cvt split (x,W1 -> cvt2 kernel; W3,vals -> L1 prologue).
// ---------------------------------------------------------------------------

typedef __attribute__((ext_vector_type(8))) short bf16x8;
typedef __attribute__((ext_vector_type(4))) float f32x4;

__device__ __forceinline__ unsigned short f2bf(float f) {
    union { float f; unsigned int u; } c; c.f = f;
    unsigned int u = c.u;
    u += 0x7fffu + ((u >> 16) & 1u);   // round-to-nearest-even
    return (unsigned short)(u >> 16);
}

__device__ __forceinline__ void async16(const void* g, void* l) {
    __builtin_amdgcn_global_load_lds(
        (const __attribute__((address_space(1))) void*)g,
        (__attribute__((address_space(3))) void*)l,
        16, 0, 0);
}

template<int N>
__device__ __forceinline__ void vm_wait() {
    asm volatile("s_waitcnt vmcnt(%0)" :: "n"(N) : "memory");
}
__device__ __forceinline__ void barrier() {
    asm volatile("" ::: "memory");
    __builtin_amdgcn_s_barrier();
    asm volatile("" ::: "memory");
}

// ---------------------------------------------------------------------------
// cvt2: f32 -> bf16 for x and W1 only (2 x 2^21 elems), grid 4096
// ---------------------------------------------------------------------------
__global__ __launch_bounds__(256) void cvt2(
    const float* __restrict__ x, const float* __restrict__ w1,
    unsigned short* __restrict__ xb, unsigned short* __restrict__ w1b)
{
    const int NE = 1 << 21;
    int e = (blockIdx.x * 256 + threadIdx.x) * 4;
    int a = e >> 21;
    int off = e & (NE - 1);
    const float* src = a ? w1 : x;
    unsigned short* dst = a ? w1b : xb;
    float4 vv = *reinterpret_cast<const float4*>(src + off);
    ushort4 o;
    o.x = f2bf(vv.x); o.y = f2bf(vv.y); o.z = f2bf(vv.z); o.w = f2bf(vv.w);
    *reinterpret_cast<ushort4*>(dst + off) = o;
}

// ---------------------------------------------------------------------------
// bf16 GEMM, B^T form (R12 structure). PRECVT: convert 2048 elems each of
// two f32 arrays per block in the prologue (producers for later kernels).
// ---------------------------------------------------------------------------
template<int BM, int BN, int MCL, int PIPE, int RELU, int OUTMODE, int PRECVT>
__global__ __launch_bounds__(256) void gemm_bt(
    const unsigned short* __restrict__ A,
    const unsigned short* __restrict__ B,
    const float* __restrict__ bias,
    void* __restrict__ C0,
    int M, int N, int K,
    const float* __restrict__ cs0, unsigned short* __restrict__ cd0,
    const float* __restrict__ cs1, unsigned short* __restrict__ cd1)
{
    constexpr int BK = 64;
    constexpr int MR = BM / 32;
    constexpr int NR = BN / 32;
    constexpr int AI = BM / 32;
    constexpr int BI = BN / 32;
    constexpr int LPS = AI + BI;
    __shared__ unsigned short As[PIPE][BM * BK];
    __shared__ unsigned short Bs[PIPE][BN * BK];

    const int t = threadIdx.x;
    const int w = t >> 6;
    const int l = t & 63;
    const int id = blockIdx.x;

    if (PRECVT) {
        // convert 2048 elems of cs0 and cs1 per block (8 per thread each)
        const int off = id * 2048 + t * 8;
        float4 a0 = *reinterpret_cast<const float4*>(cs0 + off);
        float4 a1 = *reinterpret_cast<const float4*>(cs0 + off + 4);
        float4 b0 = *reinterpret_cast<const float4*>(cs1 + off);
        float4 b1 = *reinterpret_cast<const float4*>(cs1 + off + 4);
        ushort4 o0, o1, o2, o3;
        o0.x = f2bf(a0.x); o0.y = f2bf(a0.y); o0.z = f2bf(a0.z); o0.w = f2bf(a0.w);
        o1.x = f2bf(a1.x); o1.y = f2bf(a1.y); o1.z = f2bf(a1.z); o1.w = f2bf(a1.w);
        o2.x = f2bf(b0.x); o2.y = f2bf(b0.y); o2.z = f2bf(b0.z); o2.w = f2bf(b0.w);
        o3.x = f2bf(b1.x); o3.y = f2bf(b1.y); o3.z = f2bf(b1.z); o3.w = f2bf(b1.w);
        *reinterpret_cast<ushort4*>(cd0 + off)     = o0;
        *reinterpret_cast<ushort4*>(cd0 + off + 4) = o1;
        *reinterpret_cast<ushort4*>(cd1 + off)     = o2;
        *reinterpret_cast<ushort4*>(cd1 + off + 4) = o3;
    }

    const int xcd = id & 7;
    const int j = id >> 3;
    const int mt = xcd * MCL + (j & (MCL - 1));
    const int nt = j / MCL;
    const int bm = mt * BM;
    const int bn = nt * BN;

    const int wm = (w >> 1) * (BM / 2);
    const int wn = (w & 1) * (BN / 2);

    f32x4 acc[MR][NR];
    #pragma unroll
    for (int i = 0; i < MR; ++i)
        #pragma unroll
        for (int jj = 0; jj < NR; ++jj)
            acc[i][jj] = (f32x4){0.f, 0.f, 0.f, 0.f};

    const int arow = bm + w * (BM / 4) + (l >> 3);
    const int brow = bn + w * (BN / 4) + (l >> 3);
    const int scol = ((l & 7) ^ (l >> 3)) * 8;
    const int fr = l & 15;
    const int kg = l >> 4;
    const int fq = l >> 4;

    auto stage = [&](int buf, int kt) {
        const int k0 = kt * BK;
        #pragma unroll
        for (int i = 0; i < AI; ++i)
            async16(A + (size_t)(arow + i * 8) * K + k0 + scol,
                    &As[buf][(w * (BM / 4) + i * 8) * BK]);
        #pragma unroll
        for (int i = 0; i < BI; ++i)
            async16(B + (size_t)(brow + i * 8) * K + k0 + scol,
                    &Bs[buf][(w * (BN / 4) + i * 8) * BK]);
    };

    auto compute = [&](int buf) {
        #pragma unroll
        for (int kk = 0; kk < 2; ++kk) {
            const int pc = ((kk * 4 + kg) ^ (fr & 7)) * 8;
            bf16x8 af[MR], bg[NR];
            #pragma unroll
            for (int i = 0; i < MR; ++i)
                af[i] = *reinterpret_cast<const bf16x8*>(
                    &As[buf][(wm + i * 16 + fr) * BK + pc]);
            #pragma unroll
            for (int jj = 0; jj < NR; ++jj)
                bg[jj] = *reinterpret_cast<const bf16x8*>(
                    &Bs[buf][(wn + jj * 16 + fr) * BK + pc]);
            #pragma unroll
            for (int i = 0; i < MR; ++i)
                #pragma unroll
                for (int jj = 0; jj < NR; ++jj)
                    acc[i][jj] = __builtin_amdgcn_mfma_f32_16x16x32_bf16(
                        af[i], bg[jj], acc[i][jj], 0, 0, 0);
        }
    };

    const int nK = K >> 6;
    stage(0, 0);
    stage(1, 1);
    if (PIPE == 3) stage(2, 2);
    int cur = 0;
    for (int kt = 0; kt < nK; ++kt) {
        if (PIPE == 3) {
            if (kt < nK - 2)       vm_wait<2 * LPS>();
            else if (kt == nK - 2) vm_wait<LPS>();
            else                   vm_wait<0>();
        } else {
            if (kt < nK - 1)       vm_wait<LPS>();
            else                   vm_wait<0>();
        }
        barrier();
        compute(cur);
        if (kt + PIPE < nK) {
            barrier();
            stage(cur, kt + PIPE);
        } else if (kt + 1 < nK) {
            barrier();
        }
        cur = (cur == PIPE - 1) ? 0 : cur + 1;
    }

    #pragma unroll
    for (int i = 0; i < MR; ++i) {
        const int row0 = bm + wm + i * 16 + fq * 4;
        #pragma unroll
        for (int jj = 0; jj < NR; ++jj) {
            const int col = bn + wn + jj * 16 + fr;
            const float bv = bias[col];
            #pragma unroll
            for (int v = 0; v < 4; ++v) {
                float r = acc[i][jj][v] + bv;
                if (RELU) r = fmaxf(r, 0.f);
                const size_t off = (size_t)(row0 + v) * N + col;
                if (OUTMODE == 1) ((unsigned short*)C0)[off] = f2bf(r);
                else              ((float*)C0)[off] = r;
            }
        }
    }
}

// ---------------------------------------------------------------------------
// BSR layer (R8/R12-exact): 2 nnz per K-step, grid 1024, XCD-pinned.
// ---------------------------------------------------------------------------
__global__ __launch_bounds__(256) void bsr_layer(
    const unsigned short* __restrict__ h,
    const int* __restrict__ crow,
    const int* __restrict__ cols,
    const unsigned short* __restrict__ vals,
    const float* __restrict__ b2,
    unsigned short* __restrict__ h2)
{
    __shared__ unsigned short Hs[2][128 * 64];
    __shared__ unsigned short Vs[2][32 * 64];
    __shared__ int colsS[64];
    const int t = threadIdx.x;
    const int w = t >> 6;
    const int l = t & 63;

    const int id = blockIdx.x;
    const int xcd = id & 7;
    const int j2 = id >> 3;
    const int bt = xcd * 2 + (j2 & 1);
    const int r  = j2 >> 1;
    const int bm = bt * 128;

    const int s = crow[r];
    const int cnt = crow[r + 1] - s;
    const int wrow = w * 32;

    if (t < cnt) colsS[t] = cols[s + t];

    f32x4 acc[2][2];
    #pragma unroll
    for (int i = 0; i < 2; ++i)
        #pragma unroll
        for (int jj = 0; jj < 2; ++jj)
            acc[i][jj] = (f32x4){0.f, 0.f, 0.f, 0.f};

    const int fr = l & 15;
    const int kg = l >> 4;
    const int lr = l >> 3;
    const int sc = (l & 7) ^ lr;

    auto stage = [&](int buf, int js) {
        const int n0 = s + 2 * js;
        const bool tail = (2 * js + 1 >= cnt);
        const int c0 = colsS[2 * js];
        const int c1 = tail ? c0 : colsS[2 * js + 1];
        const int n1 = tail ? n0 : n0 + 1;
        #pragma unroll
        for (int i = 0; i < 4; ++i) {
            const int row = bm + w * 32 + i * 8 + lr;
            const int col = (sc & 4) ? c1 * 32 + (sc & 3) * 8 : c0 * 32 + sc * 8;
            async16(h + (size_t)row * 2048 + col,
                    &Hs[buf][(w * 32 + i * 8) * 64]);
        }
        const int vrow = w * 8 + lr;
        if (!tail || !(sc & 4)) {
            const unsigned short* src =
                vals + (size_t)((sc & 4) ? n1 : n0) * 1024 + vrow * 32 + (sc & 3) * 8;
            async16(src, &Vs[buf][(w * 8) * 64]);
        } else {
            bf16x8 z = (bf16x8){0,0,0,0,0,0,0,0};
            *reinterpret_cast<bf16x8*>(&Vs[buf][vrow * 64 + (l & 7) * 8]) = z;
        }
    };

    auto compute = [&](int buf) {
        #pragma unroll
        for (int kk = 0; kk < 2; ++kk) {
            const int pc = ((kk * 4 + kg) ^ (fr & 7)) * 8;
            bf16x8 af[2], bg[2];
            #pragma unroll
            for (int i = 0; i < 2; ++i)
                af[i] = *reinterpret_cast<const bf16x8*>(
                    &Hs[buf][(wrow + i * 16 + fr) * 64 + pc]);
            #pragma unroll
            for (int jj = 0; jj < 2; ++jj)
                bg[jj] = *reinterpret_cast<const bf16x8*>(
                    &Vs[buf][(jj * 16 + fr) * 64 + pc]);
            #pragma unroll
            for (int i = 0; i < 2; ++i)
                #pragma unroll
                for (int jj = 0; jj < 2; ++jj)
                    acc[i][jj] = __builtin_amdgcn_mfma_f32_16x16x32_bf16(
                        af[i], bg[jj], acc[i][jj], 0, 0, 0);
        }
    };

    __syncthreads();
    const int nsteps = (cnt + 1) >> 1;
    stage(0, 0);
    if (nsteps > 1) stage(1, 1);
    int cur = 0;
    for (int js = 0; js < nsteps - 1; ++js) {
        vm_wait<5>();
        barrier();
        compute(cur);
        barrier();
        if (js + 2 < nsteps) stage(cur, js + 2);
        cur ^= 1;
    }
    vm_wait<0>();
    barrier();
    compute(cur);

    const int fq = l >> 4;
    #pragma unroll
    for (int i = 0; i < 2; ++i) {
        const int row0 = bm + wrow + i * 16 + fq * 4;
        #pragma unroll
        for (int jj = 0; jj < 2; ++jj) {
            const int col = r * 32 + jj * 16 + fr;
            const float bv = b2[col];
            #pragma unroll
            for (int v = 0; v < 4; ++v) {
                float rv = fmaxf(acc[i][jj][v] + bv, 0.f);
                h2[(size_t)(row0 + v) * 2048 + col] = f2bf(rv);
            }
        }
    }
}

// ===========================================================================
// Cooperative mega-kernel (phases separated by grid.sync)
// ===========================================================================
template<int BM, int BN, int MCL, int RELU, int OUTMODE>
__device__ void gemm_phase(
    unsigned short* __restrict__ smem,
    const unsigned short* __restrict__ A,
    const unsigned short* __restrict__ B,
    const float* __restrict__ bias,
    void* __restrict__ C,
    int M, int N, int K, int id, int t)
{
    constexpr int BK = 64;
    constexpr int MR = BM / 32;
    constexpr int NR = BN / 32;
    constexpr int AI = BM / 32;
    constexpr int BI = BN / 32;
    constexpr int LPS = AI + BI;
    unsigned short* As = smem;
    unsigned short* Bs = smem + 2 * BM * BK;

    const int w = t >> 6;
    const int l = t & 63;
    const int xcd = id & 7;
    const int j = id >> 3;
    const int mt = xcd * MCL + (j & (MCL - 1));
    const int nt = j / MCL;
    const int bm = mt * BM;
    const int bn = nt * BN;
    const int wm = (w >> 1) * (BM / 2);
    const int wn = (w & 1) * (BN / 2);

    f32x4 acc[MR][NR];
    #pragma unroll
    for (int i = 0; i < MR; ++i)
        #pragma unroll
        for (int jj = 0; jj < NR; ++jj)
            acc[i][jj] = (f32x4){0.f, 0.f, 0.f, 0.f};

    const int arow = bm + w * (BM / 4) + (l >> 3);
    const int brow = bn + w * (BN / 4) + (l >> 3);
    const int scol = ((l & 7) ^ (l >> 3)) * 8;
    const int fr = l & 15;
    const int kg = l >> 4;
    const int fq = l >> 4;

    auto stage = [&](int buf, int kt) {
        const int k0 = kt * BK;
        #pragma unroll
        for (int i = 0; i < AI; ++i)
            async16(A + (size_t)(arow + i * 8) * K + k0 + scol,
                    &As[buf * BM * BK + (w * (BM / 4) + i * 8) * BK]);
        #pragma unroll
        for (int i = 0; i < BI; ++i)
            async16(B + (size_t)(brow + i * 8) * K + k0 + scol,
                    &Bs[buf * BN * BK + (w * (BN / 4) + i * 8) * BK]);
    };

    auto compute = [&](int buf) {
        #pragma unroll
        for (int kk = 0; kk < 2; ++kk) {
            const int pc = ((kk * 4 + kg) ^ (fr & 7)) * 8;
            bf16x8 af[MR], bg[NR];
            #pragma unroll
            for (int i = 0; i < MR; ++i)
                af[i] = *reinterpret_cast<const bf16x8*>(
                    &As[buf * BM * BK + (wm + i * 16 + fr) * BK + pc]);
            #pragma unroll
            for (int jj = 0; jj < NR; ++jj)
                bg[jj] = *reinterpret_cast<const bf16x8*>(
                    &Bs[buf * BN * BK + (wn + jj * 16 + fr) * BK + pc]);
            #pragma unroll
            for (int i = 0; i < MR; ++i)
                #pragma unroll
                for (int jj = 0; jj < NR; ++jj)
                    acc[i][jj] = __builtin_amdgcn_mfma_f32_16x16x32_bf16(
                        af[i], bg[jj], acc[i][jj], 0, 0, 0);
        }
    };

    const int nK = K >> 6;
    stage(0, 0);
    stage(1, 1);
    int cur = 0;
    for (int kt = 0; kt < nK; ++kt) {
        if (kt < nK - 1) vm_wait<LPS>();
        else             vm_wait<0>();
        barrier();
        compute(cur);
        if (kt + 2 < nK) {
            barrier();
            stage(cur, kt + 2);
        } else if (kt + 1 < nK) {
            barrier();
        }
        cur ^= 1;
    }
    barrier();

    #pragma unroll
    for (int i = 0; i < MR; ++i) {
        const int row0 = bm + wm + i * 16 + fq * 4;
        #pragma unroll
        for (int jj = 0; jj < NR; ++jj) {
            const int col = bn + wn + jj * 16 + fr;
            const float bv = bias[col];
            #pragma unroll
            for (int v = 0; v < 4; ++v) {
                float r = acc[i][jj][v] + bv;
                if (RELU) r = fmaxf(r, 0.f);
                const size_t off = (size_t)(row0 + v) * N + col;
                if (OUTMODE == 1) ((unsigned short*)C)[off] = f2bf(r);
                else              ((float*)C)[off] = r;
            }
        }
    }
}

__device__ void bsr_tile(
    unsigned short* __restrict__ smem,
    const unsigned short* __restrict__ h,
    const unsigned short* __restrict__ vv,
    const int* __restrict__ colsS,
    int s, int cnt,
    const float* __restrict__ b2,
    unsigned short* __restrict__ h2,
    int bm, int r, int t)
{
    unsigned short* Hs = smem;            // [2][64*64]
    unsigned short* Vs = smem + 8192;     // [2][32*64]
    const int w = t >> 6;
    const int l = t & 63;
    const int fr = l & 15;
    const int kg = l >> 4;
    const int lr = l >> 3;
    const int sc = (l & 7) ^ lr;
    const int wrow = w * 16;

    f32x4 acc[2];
    acc[0] = (f32x4){0.f, 0.f, 0.f, 0.f};
    acc[1] = (f32x4){0.f, 0.f, 0.f, 0.f};

    auto stage = [&](int buf, int js) {
        const int n0 = s + 2 * js;
        const bool tail = (2 * js + 1 >= cnt);
        const int c0 = colsS[2 * js];
        const int c1 = tail ? c0 : colsS[2 * js + 1];
        const int n1 = tail ? n0 : n0 + 1;
        #pragma unroll
        for (int i = 0; i < 2; ++i) {
            const int row = bm + i * 32 + w * 8 + lr;
            const int col = (sc & 4) ? c1 * 32 + (sc & 3) * 8 : c0 * 32 + sc * 8;
            async16(h + (size_t)row * 2048 + col,
                    &Hs[buf * 4096 + (i * 32 + w * 8) * 64]);
        }
        const int vrow = w * 8 + lr;
        if (!tail || !(sc & 4)) {
            async16(vv + (size_t)((sc & 4) ? n1 : n0) * 1024 + vrow * 32 + (sc & 3) * 8,
                    &Vs[buf * 2048 + (w * 8) * 64]);
        } else {
            bf16x8 z = (bf16x8){0,0,0,0,0,0,0,0};
            *reinterpret_cast<bf16x8*>(&Vs[buf * 2048 + vrow * 64 + (l & 7) * 8]) = z;
        }
    };

    auto compute = [&](int buf) {
        #pragma unroll
        for (int kk = 0; kk < 2; ++kk) {
            const int pc = ((kk * 4 + kg) ^ (fr & 7)) * 8;
            bf16x8 af = *reinterpret_cast<const bf16x8*>(
                &Hs[buf * 4096 + (wrow + fr) * 64 + pc]);
            bf16x8 bg0 = *reinterpret_cast<const bf16x8*>(
                &Vs[buf * 2048 + fr * 64 + pc]);
            bf16x8 bg1 = *reinterpret_cast<const bf16x8*>(
                &Vs[buf * 2048 + (16 + fr) * 64 + pc]);
            acc[0] = __builtin_amdgcn_mfma_f32_16x16x32_bf16(af, bg0, acc[0], 0, 0, 0);
            acc[1] = __builtin_amdgcn_mfma_f32_16x16x32_bf16(af, bg1, acc[1], 0, 0, 0);
        }
    };

    const int nsteps = (cnt + 1) >> 1;
    stage(0, 0);
    if (nsteps > 1) stage(1, 1);
    int cur = 0;
    for (int js = 0; js < nsteps - 1; ++js) {
        vm_wait<3>();
        barrier();
        compute(cur);
        barrier();
        if (js + 2 < nsteps) stage(cur, js + 2);
        cur ^= 1;
    }
    vm_wait<0>();
    barrier();
    compute(cur);
    barrier();

    const int fq = l >> 4;
    #pragma unroll
    for (int jj = 0; jj < 2; ++jj) {
        const int col = r * 32 + jj * 16 + fr;
        const float bv = b2[col];
        #pragma unroll
        for (int v = 0; v < 4; ++v) {
            float rv = fmaxf(acc[jj][v] + bv, 0.f);
            h2[(size_t)(bm + wrow + fq * 4 + v) * 2048 + col] = f2bf(rv);
        }
    }
}

__global__ __launch_bounds__(256, 4) void mega(
    const float* __restrict__ x,  const float* __restrict__ W1,
    const float* __restrict__ b1, const int* __restrict__ crow,
    const int* __restrict__ cols, const float* __restrict__ vals,
    const float* __restrict__ b2, const float* __restrict__ W3,
    const float* __restrict__ b3, float* __restrict__ out,
    unsigned short* __restrict__ xb,  unsigned short* __restrict__ w1b,
    unsigned short* __restrict__ w3b, unsigned short* __restrict__ vb,
    unsigned short* __restrict__ hb,  unsigned short* __restrict__ h2b)
{
    __shared__ __align__(16) unsigned short smem[16384];   // 32 KB
    cg::grid_group grid = cg::this_grid();
    const int t = threadIdx.x;
    const int id = blockIdx.x;

    {   // phase 0: cvt (8 x 1M-elem passes)
        const int gid = id * 256 + t;
        #pragma unroll
        for (int pass = 0; pass < 8; ++pass) {
            const int E = (pass << 20) + gid * 4;
            const int a = E >> 21;
            const int off = E & ((1 << 21) - 1);
            const float* src = (a == 0) ? x : (a == 1) ? W1 : (a == 2) ? W3 : vals;
            unsigned short* dst = (a == 0) ? xb : (a == 1) ? w1b : (a == 2) ? w3b : vb;
            float4 vv4 = *reinterpret_cast<const float4*>(src + off);
            ushort4 o;
            o.x = f2bf(vv4.x); o.y = f2bf(vv4.y);
            o.z = f2bf(vv4.z); o.w = f2bf(vv4.w);
            *reinterpret_cast<ushort4*>(dst + off) = o;
        }
    }
    __threadfence();
    grid.sync();

    gemm_phase<64, 64, 4, 1, 1>(smem, xb, w1b, b1, hb, 2048, 2048, 1024, id, t);
    __threadfence();
    grid.sync();

    {   // phase 2: BSR, two 64-row tiles per block (same r)
        const int r   = id & 63;
        const int bt0 = id >> 6;
        const int s   = crow[r];
        const int cnt = crow[r + 1] - s;
        int* colsS = (int*)(smem + 12288);
        if (t < 64 && t < cnt) colsS[t] = cols[s + t];
        barrier();
        bsr_tile(smem, hb, vb, colsS, s, cnt, b2, h2b, bt0 * 64, r, t);
        bsr_tile(smem, hb, vb, colsS, s, cnt, b2, h2b, (bt0 + 16) * 64, r, t);
    }
    __threadfence();
    grid.sync();

    gemm_phase<64, 32, 4, 0, 0>(smem, h2b, w3b, b3, out, 2048, 1024, 2048, id, t);
}

// ---------------------------------------------------------------------------
extern "C" void kernel_launch(void* const* d_in, const int* in_sizes, int n_in,
                              void* d_out, int out_size, void* d_ws, size_t ws_size,
                              hipStream_t stream) {
    const float* x    = (const float*)d_in[0];
    const float* W1   = (const float*)d_in[1];
    const float* b1   = (const float*)d_in[2];
    const int*   crow = (const int*)d_in[3];
    const int*   cols = (const int*)d_in[4];
    const float* vals = (const float*)d_in[5];
    const float* b2   = (const float*)d_in[6];
    const float* W3   = (const float*)d_in[7];
    const float* b3   = (const float*)d_in[8];
    float* out = (float*)d_out;

    const int NE = 2 * 1024 * 1024;
    unsigned short* xb  = (unsigned short*)d_ws;
    unsigned short* w1b = xb  + NE;
    unsigned short* w3b = w1b + NE;
    unsigned short* vb  = w3b + NE;
    unsigned short* hb  = vb  + NE;
    unsigned short* h2b = hb  + 2 * NE;

    void* args[] = {
        (void*)&x, (void*)&W1, (void*)&b1, (void*)&crow, (void*)&cols,
        (void*)&vals, (void*)&b2, (void*)&W3, (void*)&b3, (void*)&out,
        (void*)&xb, (void*)&w1b, (void*)&w3b, (void*)&vb,
        (void*)&hb, (void*)&h2b
    };
    hipError_t err = hipLaunchCooperativeKernel(
        (const void*)mega, dim3(1024), dim3(256), args, 0, stream);

    if (err != hipSuccess) {
        // ---- fallback: proven R12 path (+ cvt split into L1 prologue) ----
        cvt2<<<4096, 256, 0, stream>>>(x, W1, xb, w1b);
        // L1 (also converts W3 -> w3b and vals -> vb in its prologue)
        gemm_bt<64, 64, 4, 2, 1, 1, 1><<<1024, 256, 0, stream>>>(
            xb, w1b, b1, hb, 2048, 2048, 1024, W3, w3b, vals, vb);
        bsr_layer<<<1024, 256, 0, stream>>>(hb, crow, cols, vb, b2, h2b);
        gemm_bt<64, 32, 4, 2, 0, 0, 0><<<1024, 256, 0, stream>>>(
            h2b, w3b, b3, out, 2048, 1024, 2048,
            nullptr, nullptr, nullptr, nullptr);
    }

    (void)in_sizes; (void)n_in; (void)out_size; (void)ws_size;
}

// Round 15
// 75.946 us; speedup vs baseline: 9.4847x; 9.4847x over previous
//
#include <hip/hip_runtime.h>
#include <hip/hip_bf16.h>

// ---------------------------------------------------------------------------
// BlockedMLP: out = (relu(bsr(relu(x@W1^T+b1))+b2)) @ W3^T + b3
// B=2048, IN=1024, H=2048, OUT=1024, BS=32, RB=CB=64, 32 blocks/row
// Round 15: R14's fallback path, unconditional (cooperative grid.sync
// measured at ~200us/sync on MI355X R14 — dead end).
//   cvt2 (x,W1) -> L1 64x64 PIPE2 (+prologue-cvt of W3,vals, hidden under
//   pipeline fill) -> BSR (R8-exact, 4/CU) -> L3 64x32 PIPE2 (4/CU).
// All pieces individually proven: R12 = 76.6us; this removes half of cvt.
// ---------------------------------------------------------------------------

typedef __attribute__((ext_vector_type(8))) short bf16x8;
typedef __attribute__((ext_vector_type(4))) float f32x4;

__device__ __forceinline__ unsigned short f2bf(float f) {
    union { float f; unsigned int u; } c; c.f = f;
    unsigned int u = c.u;
    u += 0x7fffu + ((u >> 16) & 1u);   // round-to-nearest-even
    return (unsigned short)(u >> 16);
}

__device__ __forceinline__ void async16(const void* g, void* l) {
    __builtin_amdgcn_global_load_lds(
        (const __attribute__((address_space(1))) void*)g,
        (__attribute__((address_space(3))) void*)l,
        16, 0, 0);
}

template<int N>
__device__ __forceinline__ void vm_wait() {
    asm volatile("s_waitcnt vmcnt(%0)" :: "n"(N) : "memory");
}
__device__ __forceinline__ void barrier() {
    asm volatile("" ::: "memory");
    __builtin_amdgcn_s_barrier();
    asm volatile("" ::: "memory");
}

// ---------------------------------------------------------------------------
// cvt2: f32 -> bf16 for x and W1 only (2 x 2^21 elems), grid 4096
// ---------------------------------------------------------------------------
__global__ __launch_bounds__(256) void cvt2(
    const float* __restrict__ x, const float* __restrict__ w1,
    unsigned short* __restrict__ xb, unsigned short* __restrict__ w1b)
{
    const int NE = 1 << 21;
    int e = (blockIdx.x * 256 + threadIdx.x) * 4;
    int a = e >> 21;
    int off = e & (NE - 1);
    const float* src = a ? w1 : x;
    unsigned short* dst = a ? w1b : xb;
    float4 vv = *reinterpret_cast<const float4*>(src + off);
    ushort4 o;
    o.x = f2bf(vv.x); o.y = f2bf(vv.y); o.z = f2bf(vv.z); o.w = f2bf(vv.w);
    *reinterpret_cast<ushort4*>(dst + off) = o;
}

// ---------------------------------------------------------------------------
// bf16 GEMM, B^T form (R12 structure): BM x BN tile, BK=64, 4 waves (2x2),
// PIPE-deep LDS dbuf, two-barrier counted-vmcnt, XOR swizzle chunk^(row&7),
// XCD-pinned 1-D grid decode.
// PRECVT: convert 2048 elems each of two f32 arrays per block in the
// prologue (producers for LATER kernels; hidden under pipeline fill).
// OUTMODE: 0 = f32+bias, 1 = bf16+bias.
// ---------------------------------------------------------------------------
template<int BM, int BN, int MCL, int PIPE, int RELU, int OUTMODE, int PRECVT>
__global__ __launch_bounds__(256) void gemm_bt(
    const unsigned short* __restrict__ A,
    const unsigned short* __restrict__ B,
    const float* __restrict__ bias,
    void* __restrict__ C0,
    int M, int N, int K,
    const float* __restrict__ cs0, unsigned short* __restrict__ cd0,
    const float* __restrict__ cs1, unsigned short* __restrict__ cd1)
{
    constexpr int BK = 64;
    constexpr int MR = BM / 32;
    constexpr int NR = BN / 32;
    constexpr int AI = BM / 32;
    constexpr int BI = BN / 32;
    constexpr int LPS = AI + BI;
    __shared__ unsigned short As[PIPE][BM * BK];
    __shared__ unsigned short Bs[PIPE][BN * BK];

    const int t = threadIdx.x;
    const int w = t >> 6;
    const int l = t & 63;
    const int id = blockIdx.x;

    const int xcd = id & 7;
    const int j = id >> 3;
    const int mt = xcd * MCL + (j & (MCL - 1));
    const int nt = j / MCL;
    const int bm = mt * BM;
    const int bn = nt * BN;

    const int wm = (w >> 1) * (BM / 2);
    const int wn = (w & 1) * (BN / 2);

    f32x4 acc[MR][NR];
    #pragma unroll
    for (int i = 0; i < MR; ++i)
        #pragma unroll
        for (int jj = 0; jj < NR; ++jj)
            acc[i][jj] = (f32x4){0.f, 0.f, 0.f, 0.f};

    const int arow = bm + w * (BM / 4) + (l >> 3);
    const int brow = bn + w * (BN / 4) + (l >> 3);
    const int scol = ((l & 7) ^ (l >> 3)) * 8;
    const int fr = l & 15;
    const int kg = l >> 4;
    const int fq = l >> 4;

    auto stage = [&](int buf, int kt) {
        const int k0 = kt * BK;
        #pragma unroll
        for (int i = 0; i < AI; ++i)
            async16(A + (size_t)(arow + i * 8) * K + k0 + scol,
                    &As[buf][(w * (BM / 4) + i * 8) * BK]);
        #pragma unroll
        for (int i = 0; i < BI; ++i)
            async16(B + (size_t)(brow + i * 8) * K + k0 + scol,
                    &Bs[buf][(w * (BN / 4) + i * 8) * BK]);
    };

    auto compute = [&](int buf) {
        #pragma unroll
        for (int kk = 0; kk < 2; ++kk) {
            const int pc = ((kk * 4 + kg) ^ (fr & 7)) * 8;
            bf16x8 af[MR], bg[NR];
            #pragma unroll
            for (int i = 0; i < MR; ++i)
                af[i] = *reinterpret_cast<const bf16x8*>(
                    &As[buf][(wm + i * 16 + fr) * BK + pc]);
            #pragma unroll
            for (int jj = 0; jj < NR; ++jj)
                bg[jj] = *reinterpret_cast<const bf16x8*>(
                    &Bs[buf][(wn + jj * 16 + fr) * BK + pc]);
            #pragma unroll
            for (int i = 0; i < MR; ++i)
                #pragma unroll
                for (int jj = 0; jj < NR; ++jj)
                    acc[i][jj] = __builtin_amdgcn_mfma_f32_16x16x32_bf16(
                        af[i], bg[jj], acc[i][jj], 0, 0, 0);
        }
    };

    const int nK = K >> 6;
    stage(0, 0);
    stage(1, 1);
    if (PIPE == 3) stage(2, 2);

    if (PRECVT) {
        // convert 2048 elems each of cs0/cs1 per block (8 per thread each);
        // runs while the first staged tiles are in flight. These f32 loads
        // enter the vmcnt queue AFTER the staged tiles, so the pipeline's
        // counted waits (which count newest-first) remain conservative-safe:
        // wait<LPS> still guarantees buf[cur]'s loads are done.
        const int off = id * 2048 + t * 8;
        float4 a0 = *reinterpret_cast<const float4*>(cs0 + off);
        float4 a1 = *reinterpret_cast<const float4*>(cs0 + off + 4);
        float4 b0 = *reinterpret_cast<const float4*>(cs1 + off);
        float4 b1 = *reinterpret_cast<const float4*>(cs1 + off + 4);
        ushort4 o0, o1, o2, o3;
        o0.x = f2bf(a0.x); o0.y = f2bf(a0.y); o0.z = f2bf(a0.z); o0.w = f2bf(a0.w);
        o1.x = f2bf(a1.x); o1.y = f2bf(a1.y); o1.z = f2bf(a1.z); o1.w = f2bf(a1.w);
        o2.x = f2bf(b0.x); o2.y = f2bf(b0.y); o2.z = f2bf(b0.z); o2.w = f2bf(b0.w);
        o3.x = f2bf(b1.x); o3.y = f2bf(b1.y); o3.z = f2bf(b1.z); o3.w = f2bf(b1.w);
        *reinterpret_cast<ushort4*>(cd0 + off)     = o0;
        *reinterpret_cast<ushort4*>(cd0 + off + 4) = o1;
        *reinterpret_cast<ushort4*>(cd1 + off)     = o2;
        *reinterpret_cast<ushort4*>(cd1 + off + 4) = o3;
    }

    int cur = 0;
    for (int kt = 0; kt < nK; ++kt) {
        if (PIPE == 3) {
            if (kt < nK - 2)       vm_wait<2 * LPS>();
            else if (kt == nK - 2) vm_wait<LPS>();
            else                   vm_wait<0>();
        } else {
            if (kt < nK - 1)       vm_wait<LPS>();
            else                   vm_wait<0>();
        }
        barrier();
        compute(cur);
        if (kt + PIPE < nK) {
            barrier();
            stage(cur, kt + PIPE);
        } else if (kt + 1 < nK) {
            barrier();
        }
        cur = (cur == PIPE - 1) ? 0 : cur + 1;
    }

    // epilogue: C/D layout col = l&15, row = (l>>4)*4 + v
    #pragma unroll
    for (int i = 0; i < MR; ++i) {
        const int row0 = bm + wm + i * 16 + fq * 4;
        #pragma unroll
        for (int jj = 0; jj < NR; ++jj) {
            const int col = bn + wn + jj * 16 + fr;
            const float bv = bias[col];
            #pragma unroll
            for (int v = 0; v < 4; ++v) {
                float r = acc[i][jj][v] + bv;
                if (RELU) r = fmaxf(r, 0.f);
                const size_t off = (size_t)(row0 + v) * N + col;
                if (OUTMODE == 1) ((unsigned short*)C0)[off] = f2bf(r);
                else              ((float*)C0)[off] = r;
            }
        }
    }
}

// ---------------------------------------------------------------------------
// BSR layer (R8-exact): 2 nnz blocks per K-step (K-concat), counted-vmcnt,
// grid 1024 (4 blocks/CU), XCD-pinned, 128B LDS rows XOR-swizzled.
// ---------------------------------------------------------------------------
__global__ __launch_bounds__(256) void bsr_layer(
    const unsigned short* __restrict__ h,     // 2048 x 2048 bf16
    const int* __restrict__ crow,
    const int* __restrict__ cols,
    const unsigned short* __restrict__ vals,  // nnz x 32 x 32 bf16
    const float* __restrict__ b2,
    unsigned short* __restrict__ h2)          // 2048 x 2048 bf16
{
    __shared__ unsigned short Hs[2][128 * 64];
    __shared__ unsigned short Vs[2][32 * 64];
    __shared__ int colsS[64];
    const int t = threadIdx.x;
    const int w = t >> 6;
    const int l = t & 63;

    const int id = blockIdx.x;
    const int xcd = id & 7;
    const int j2 = id >> 3;
    const int bt = xcd * 2 + (j2 & 1);
    const int r  = j2 >> 1;
    const int bm = bt * 128;

    const int s = crow[r];
    const int cnt = crow[r + 1] - s;
    const int wrow = w * 32;

    if (t < cnt) colsS[t] = cols[s + t];

    f32x4 acc[2][2];
    #pragma unroll
    for (int i = 0; i < 2; ++i)
        #pragma unroll
        for (int jj = 0; jj < 2; ++jj)
            acc[i][jj] = (f32x4){0.f, 0.f, 0.f, 0.f};

    const int fr = l & 15;
    const int kg = l >> 4;
    const int lr = l >> 3;
    const int sc = (l & 7) ^ lr;

    auto stage = [&](int buf, int js) {
        const int n0 = s + 2 * js;
        const bool tail = (2 * js + 1 >= cnt);
        const int c0 = colsS[2 * js];
        const int c1 = tail ? c0 : colsS[2 * js + 1];
        const int n1 = tail ? n0 : n0 + 1;
        #pragma unroll
        for (int i = 0; i < 4; ++i) {
            const int row = bm + w * 32 + i * 8 + lr;
            const int col = (sc & 4) ? c1 * 32 + (sc & 3) * 8 : c0 * 32 + sc * 8;
            async16(h + (size_t)row * 2048 + col,
                    &Hs[buf][(w * 32 + i * 8) * 64]);
        }
        const int vrow = w * 8 + lr;
        if (!tail || !(sc & 4)) {
            const unsigned short* src =
                vals + (size_t)((sc & 4) ? n1 : n0) * 1024 + vrow * 32 + (sc & 3) * 8;
            async16(src, &Vs[buf][(w * 8) * 64]);
        } else {
            bf16x8 z = (bf16x8){0,0,0,0,0,0,0,0};
            *reinterpret_cast<bf16x8*>(&Vs[buf][vrow * 64 + (l & 7) * 8]) = z;
        }
    };

    auto compute = [&](int buf) {
        #pragma unroll
        for (int kk = 0; kk < 2; ++kk) {
            const int pc = ((kk * 4 + kg) ^ (fr & 7)) * 8;
            bf16x8 af[2], bg[2];
            #pragma unroll
            for (int i = 0; i < 2; ++i)
                af[i] = *reinterpret_cast<const bf16x8*>(
                    &Hs[buf][(wrow + i * 16 + fr) * 64 + pc]);
            #pragma unroll
            for (int jj = 0; jj < 2; ++jj)
                bg[jj] = *reinterpret_cast<const bf16x8*>(
                    &Vs[buf][(jj * 16 + fr) * 64 + pc]);
            #pragma unroll
            for (int i = 0; i < 2; ++i)
                #pragma unroll
                for (int jj = 0; jj < 2; ++jj)
                    acc[i][jj] = __builtin_amdgcn_mfma_f32_16x16x32_bf16(
                        af[i], bg[jj], acc[i][jj], 0, 0, 0);
        }
    };

    __syncthreads();
    const int nsteps = (cnt + 1) >> 1;
    stage(0, 0);
    if (nsteps > 1) stage(1, 1);
    int cur = 0;
    for (int js = 0; js < nsteps - 1; ++js) {
        vm_wait<5>();
        barrier();
        compute(cur);
        barrier();
        if (js + 2 < nsteps) stage(cur, js + 2);
        cur ^= 1;
    }
    vm_wait<0>();
    barrier();
    compute(cur);

    const int fq = l >> 4;
    #pragma unroll
    for (int i = 0; i < 2; ++i) {
        const int row0 = bm + wrow + i * 16 + fq * 4;
        #pragma unroll
        for (int jj = 0; jj < 2; ++jj) {
            const int col = r * 32 + jj * 16 + fr;
            const float bv = b2[col];
            #pragma unroll
            for (int v = 0; v < 4; ++v) {
                float rv = fmaxf(acc[i][jj][v] + bv, 0.f);
                h2[(size_t)(row0 + v) * 2048 + col] = f2bf(rv);
            }
        }
    }
}

// ---------------------------------------------------------------------------
extern "C" void kernel_launch(void* const* d_in, const int* in_sizes, int n_in,
                              void* d_out, int out_size, void* d_ws, size_t ws_size,
                              hipStream_t stream) {
    const float* x    = (const float*)d_in[0];   // 2048x1024
    const float* W1   = (const float*)d_in[1];   // 2048x1024
    const float* b1   = (const float*)d_in[2];   // 2048
    const int*   crow = (const int*)d_in[3];     // 65
    const int*   cols = (const int*)d_in[4];     // 2048
    const float* vals = (const float*)d_in[5];   // 2048x32x32
    const float* b2   = (const float*)d_in[6];   // 2048
    const float* W3   = (const float*)d_in[7];   // 1024x2048
    const float* b3   = (const float*)d_in[8];   // 1024
    float* out = (float*)d_out;                  // 2048x1024 f32

    const int NE = 2 * 1024 * 1024;
    unsigned short* xb  = (unsigned short*)d_ws;         // [0,  4MB)
    unsigned short* w1b = xb  + NE;                      // [4,  8MB)
    unsigned short* w3b = w1b + NE;                      // [8, 12MB)
    unsigned short* vb  = w3b + NE;                      // [12,16MB)
    unsigned short* hb  = vb  + NE;                      // [16,24MB)
    unsigned short* h2b = hb  + 2 * NE;                  // [24,32MB)

    // cvt x, W1 (L1's operands)
    cvt2<<<4096, 256, 0, stream>>>(x, W1, xb, w1b);
    // L1: h = relu(x @ W1^T + b1), 64x64, grid 1024 (5/CU), PIPE2;
    // prologue converts W3 -> w3b and vals -> vb (consumers launch later)
    gemm_bt<64, 64, 4, 2, 1, 1, 1><<<1024, 256, 0, stream>>>(
        xb, w1b, b1, hb, 2048, 2048, 1024, W3, w3b, vals, vb);
    // BSR + relu, grid 1024 (4/CU)
    bsr_layer<<<1024, 256, 0, stream>>>(hb, crow, cols, vb, b2, h2b);
    // L3: out = h2 @ W3^T + b3, 64x32, grid 1024 (4/CU), PIPE2
    gemm_bt<64, 32, 4, 2, 0, 0, 0><<<1024, 256, 0, stream>>>(
        h2b, w3b, b3, out, 2048, 1024, 2048,
        nullptr, nullptr, nullptr, nullptr);

    (void)in_sizes; (void)n_in; (void)out_size; (void)ws_size;
}